// Round 2
// baseline (273.820 us; speedup 1.0000x reference)
//
#include <hip/hip_runtime.h>

// SpaNn belief-propagation decoder, sparse reformulation (round 4).
// N=1024 vars x DV=4 edges = E=4096; M=512 checks x DC=8.
// var_of_edge[e] = e>>2 (static). Check connectivity recovered from
// w_odd_to_even via each row's leftmost nonzero column f[e]:
// for a check with edges e1<e2<...<e8, f(e1)=e2 and f(ek>=2)=e1, so
//   key(e) = (f(f(e))==e && e<f(e)) ? e : f(e)
// maps every edge to its check's minimum edge.
//
// Round-4 change: single fused dispatch. 256 blocks x 1024 threads
// (1 block/CU at 82 KB LDS, all co-resident). Every block scans 16 rows
// (one wave per row, depth-4 prefetch). Block 0 additionally solves:
// it inits f-independent state overlapped with the scan, then spins on
// per-row release/acquire flags. Deadlock-free (only block 0 waits;
// scanners always retire). Poison-robust: full-dword non-byte-repeat
// magic; stale-magic carryover is benign (f is deterministic).
// All FP op sequences bitwise-identical to rounds 2/3 (absmax 0.0).

#define En 4096
#define Nn 1024
#define Mn 512
#define EPSF 1.1920929e-07f
#define MAGIC 0x7E57A11F

__global__ __launch_bounds__(1024) void spa_fused(
    const float* __restrict__ w, const float* __restrict__ x,
    float* __restrict__ out, int* __restrict__ f_g,
    int* __restrict__ flags) {
  __shared__ int   fs[En];       // 16 KB  leftmost-peer
  __shared__ int   slotmap[En];  // 16 KB  min-edge -> check slot
  __shared__ int   ce[En];       // 16 KB  check -> 8 edges (ascending)
  __shared__ float ods[En];      // 16 KB  tanh(odd) messages
  __shared__ float evs[En];      // 16 KB  even messages
  __shared__ int   cnt[Mn];      //  2 KB  fill position per check
  __shared__ int   wtot[16];     //        min-edge count per wave

  const int t    = threadIdx.x;
  const int lane = t & 63;
  const int wv   = t >> 6;

  // ======== phase 1: every block scans 16 rows, one wave per row ========
  // Find leftmost nonzero column. 1 KB chunks, ballot exit, 4 chunks in
  // flight (dependent-stall/step ~ latency/4). Every row has 7 nonzeros,
  // so leftmost col <= 4089 and the loop terminates by base = 3840.
  {
    const int row = blockIdx.x * 16 + wv;
    const float4* rowp = (const float4*)(w + (size_t)row * En);
    float4 v0 = rowp[lane];
    float4 v1 = rowp[64 + lane];
    float4 v2 = rowp[128 + lane];
    float4 v3 = rowp[192 + lane];
    for (int base = 0;; base += 256) {
      bool any = (v0.x != 0.0f) | (v0.y != 0.0f) | (v0.z != 0.0f) | (v0.w != 0.0f);
      unsigned long long m = __ballot(any);
      if (m) {
        if (lane == __ffsll(m) - 1) {
          int off = (v0.x != 0.0f) ? 0 : (v0.y != 0.0f) ? 1 : (v0.z != 0.0f) ? 2 : 3;
          f_g[row] = base + 4 * lane + off;          // plain store, then
          __hip_atomic_store(&flags[row], MAGIC,     // release orders it
                             __ATOMIC_RELEASE, __HIP_MEMORY_SCOPE_AGENT);
        }
        break;
      }
      v0 = v1; v1 = v2; v2 = v3;
      int nxt = base + 1024;                // floats; next chunk to fetch
      if (nxt > En - 256) nxt = En - 256;   // clamp: redundant, never OOB,
      v3 = rowp[(nxt >> 2) + lane];         // never consumed past 3840
    }
  }
  if (blockIdx.x != 0) return;

  // ======== block 0: solver ========
  // f-independent init first -> overlaps with the other blocks' scans.
  if (t < Mn) cnt[t] = 0;
  const float xt  = x[t];
  const float th0 = tanhf(0.5f * xt);
  *((float4*)&ods[4 * t]) = make_float4(th0, th0, th0, th0);

  // wait for all rows (own 16 are already flagged)
#pragma unroll
  for (int k = 0; k < 4; ++k) {
    while (__hip_atomic_load(&flags[t + k * 1024], __ATOMIC_ACQUIRE,
                             __HIP_MEMORY_SCOPE_AGENT) != MAGIC)
      __builtin_amdgcn_s_sleep(1);
  }
  __syncthreads();  // every thread acquired -> all f_g writes visible

  // ---- preamble: load f, derive keys, assign check slots (ballot scan) ----
  int4 fv = ((const int4*)f_g)[t];
  *((int4*)&fs[4 * t]) = fv;
  __syncthreads();

  const int fearr[4] = {fv.x, fv.y, fv.z, fv.w};
  int  keys[4];
  bool ismin[4];
#pragma unroll
  for (int k = 0; k < 4; ++k) {
    int e   = 4 * t + k;
    int fe  = fearr[k];
    int ffe = fs[fe];
    keys[k]  = (ffe == e && e < fe) ? e : fe;  // check's minimum edge
    ismin[k] = (keys[k] == e);
  }
  // unique slot per min-edge: wave-local rank via ballot+popcount, then
  // per-wave base via a tiny LDS scan. Slot ordering is arbitrary.
  const unsigned long long ltmask = (1ull << lane) - 1ull;
  int pre = 0;
  int rank[4];
#pragma unroll
  for (int k = 0; k < 4; ++k) {
    unsigned long long b = __ballot(ismin[k]);
    rank[k] = pre + (int)__popcll(b & ltmask);
    pre    += (int)__popcll(b);
  }
  if (lane == 0) wtot[wv] = pre;
  __syncthreads();
  int wbase = 0;
  for (int w2 = 0; w2 < wv; ++w2) wbase += wtot[w2];  // broadcast LDS reads
#pragma unroll
  for (int k = 0; k < 4; ++k)
    if (ismin[k]) slotmap[4 * t + k] = wbase + rank[k];
  __syncthreads();

  // ---- scatter edges into their check's list (unordered) ----
#pragma unroll
  for (int k = 0; k < 4; ++k) {
    int c = slotmap[keys[k]];
    int p = atomicAdd(&cnt[c], 1);
    ce[c * 8 + p] = 4 * t + k;
  }
  __syncthreads();

  // ---- restore ascending edge order: Batcher 8-sorter, registers only ----
  if (t < Mn) {
    int4 a = *((int4*)&ce[t * 8]);
    int4 b = *((int4*)&ce[t * 8 + 4]);
    int s0 = a.x, s1 = a.y, s2 = a.z, s3 = a.w;
    int s4 = b.x, s5 = b.y, s6 = b.z, s7 = b.w;
#define CEX(p, q) { int lo_ = min(p, q), hi_ = max(p, q); p = lo_; q = hi_; }
    CEX(s0, s1); CEX(s2, s3); CEX(s0, s2); CEX(s1, s3); CEX(s1, s2);  // sort lo
    CEX(s4, s5); CEX(s6, s7); CEX(s4, s6); CEX(s5, s7); CEX(s5, s6);  // sort hi
    CEX(s0, s4); CEX(s2, s6); CEX(s1, s5); CEX(s3, s7);               // merge
    CEX(s2, s4); CEX(s3, s5);
    CEX(s1, s2); CEX(s3, s4); CEX(s5, s6);
#undef CEX
    *((int4*)&ce[t * 8])     = make_int4(s0, s1, s2, s3);
    *((int4*)&ce[t * 8 + 4]) = make_int4(s4, s5, s6, s7);
  }
  __syncthreads();

  // ---- BP iterations (bitwise-identical to reference ordering) ----
  const int c = t >> 1;   // check owned by this thread pair
  const int h = t & 1;    // which half of the 8 outputs this thread emits
  int e[8];
#pragma unroll
  for (int k = 0; k < 8; ++k) e[k] = ce[c * 8 + k];  // loop-invariant
  int eo[4];
#pragma unroll
  for (int kk = 0; kk < 4; ++kk) eo[kk] = h ? e[4 + kk] : e[kk];

  for (int it = 0; it < 5; ++it) {
    // even phase: every thread computes all 8 leave-one-out products
    // (exact same multiply sequence as np.prod), then atanhf for only
    // its half -> 4 transcendentals/thread, all 16 waves busy.
    float f[8];
#pragma unroll
    for (int k = 0; k < 8; ++k) {
      float o = ods[e[k]];
      f[k] = (o == 0.0f) ? 1.0f : o;  // reference's zero->identity subst
    }
    float v[8];
    float p = 1.0f;
#pragma unroll
    for (int k = 0; k < 8; ++k) {
      float vv = p;                   // p = ((1*f0)*f1)*...*f[k-1] (exact prefix)
#pragma unroll
      for (int j = k + 1; j < 8; ++j) vv *= f[j];  // continue left-to-right
      v[k] = vv;
      p *= f[k];
    }
#pragma unroll
    for (int kk = 0; kk < 4; ++kk) {
      float vv = h ? v[4 + kk] : v[kk];
      if (vv >= 1.0f)       vv =  1.0f - EPSF;
      else if (vv <= -1.0f) vv = -1.0f + EPSF;
      evs[eo[kk]] = 2.0f * atanhf(vv);
    }
    __syncthreads();

    if (it < 4) {
      float4 e4 = *((const float4*)&evs[4 * t]);
      float ev[4] = {e4.x, e4.y, e4.z, e4.w};
      float od[4];
#pragma unroll
      for (int k = 0; k < 4; ++k) {
        float s = 0.0f;
#pragma unroll
        for (int j = 0; j < 4; ++j)
          if (j != k) s += ev[j];  // ascending 3-term sum, same op order
        od[k] = tanhf(0.5f * (xt + s));
      }
      *((float4*)&ods[4 * t]) = make_float4(od[0], od[1], od[2], od[3]);
      __syncthreads();
    }
  }

  // ---- output: sigmoid(x + sum of final evens), same op order ----
  float4 e4 = *((const float4*)&evs[4 * t]);
  float s4  = e4.x + e4.y + e4.z + e4.w;
  float z   = xt + s4;
  out[t]    = 1.0f / (1.0f + expf(-z));
}

// ---------------------------------------------------------------------------
extern "C" void kernel_launch(void* const* d_in, const int* in_sizes, int n_in,
                              void* d_out, int out_size, void* d_ws,
                              size_t ws_size, hipStream_t stream) {
  const float* x    = (const float*)d_in[0];  // [1024]
  const float* w_oe = (const float*)d_in[2];  // w_odd_to_even [4096,4096]
  float* out = (float*)d_out;

  int* f     = (int*)d_ws;        // [4096] leftmost peer per edge
  int* flags = (int*)d_ws + En;   // [4096] per-row completion flags

  spa_fused<<<dim3(256), dim3(1024), 0, stream>>>(w_oe, x, out, f, flags);
}

// Round 3
// 174.959 us; speedup vs baseline: 1.5651x; 1.5651x over previous
//
#include <hip/hip_runtime.h>

// SpaNn belief-propagation decoder, sparse reformulation (round 5).
// N=1024 vars x DV=4 edges = E=4096; M=512 checks x DC=8.
// var_of_edge[e] = e>>2 (static). Check connectivity recovered from
// w_odd_to_even via each row's leftmost nonzero column f[e]:
// for a check with edges e1<e2<...<e8, f(e1)=e2 and f(ek>=2)=e1, so
//   key(e) = (f(f(e))==e && e<f(e)) ? e : f(e)
// maps every edge to its check's minimum edge.
//
// Round-5 change vs round 4: FENCE-FREE fused sync. Round 4's per-row
// RELEASE/ACQUIRE agent atomics cost 148 us (serialized L2 writebacks +
// invalidate thrash). Now: f is written with RELAXED/AGENT stores
// (cache-bypass to MALL, no fence), __syncthreads' implicit vmcnt(0)
// drain guarantees completion, then ONE relaxed per-block flag (256
// total). Block 0 spins on the flags with RELAXED/AGENT loads (bypass,
// no invalidates) and reads f the same way. No dirty-line race: the
// poison fill's dispatch-completion flush precedes us, and f/flags are
// never read through L1/L2. Deadlock-free: only block 0 waits.
// Solve body bit-identical to rounds 2-4 (absmax 0.0).

#define En 4096
#define Nn 1024
#define Mn 512
#define EPSF 1.1920929e-07f
#define MAGIC 0x7E57A11F

__global__ __launch_bounds__(1024) void spa_fused(
    const float* __restrict__ w, const float* __restrict__ x,
    float* __restrict__ out, int* __restrict__ f_g,
    int* __restrict__ blkflag) {
  __shared__ int   fs[En];       // 16 KB  leftmost-peer
  __shared__ int   slotmap[En];  // 16 KB  min-edge -> check slot
  __shared__ int   ce[En];       // 16 KB  check -> 8 edges (ascending)
  __shared__ float ods[En];      // 16 KB  tanh(odd) messages
  __shared__ float evs[En];      // 16 KB  even messages
  __shared__ int   cnt[Mn];      //  2 KB  fill position per check
  __shared__ int   wtot[16];     //        min-edge count per wave

  const int t    = threadIdx.x;
  const int lane = t & 63;
  const int wv   = t >> 6;

  // ======== phase 1: every block scans 16 rows, one wave per row ========
  // Find leftmost nonzero column. 1 KB chunks, ballot exit, 4 chunks in
  // flight. Every row has 7 nonzeros, so leftmost col <= 4089 and the
  // loop always terminates by base = 3840.
  {
    const int row = blockIdx.x * 16 + wv;
    const float4* rowp = (const float4*)(w + (size_t)row * En);
    float4 v0 = rowp[lane];
    float4 v1 = rowp[64 + lane];
    float4 v2 = rowp[128 + lane];
    float4 v3 = rowp[192 + lane];
    for (int base = 0;; base += 256) {
      bool any = (v0.x != 0.0f) | (v0.y != 0.0f) | (v0.z != 0.0f) | (v0.w != 0.0f);
      unsigned long long m = __ballot(any);
      if (m) {
        if (lane == __ffsll(m) - 1) {
          int off = (v0.x != 0.0f) ? 0 : (v0.y != 0.0f) ? 1 : (v0.z != 0.0f) ? 2 : 3;
          // cache-bypass store to the MALL coherence point; no fence
          __hip_atomic_store(&f_g[row], base + 4 * lane + off,
                             __ATOMIC_RELAXED, __HIP_MEMORY_SCOPE_AGENT);
        }
        break;
      }
      v0 = v1; v1 = v2; v2 = v3;
      int nxt = base + 1024;                // floats; next chunk to fetch
      if (nxt > En - 256) nxt = En - 256;   // clamp: redundant, never OOB
      v3 = rowp[(nxt >> 2) + lane];
    }
  }
  // __syncthreads lowers with s_waitcnt vmcnt(0): all 16 bypass stores of
  // this block are complete (visible at MALL) before the flag goes up.
  __syncthreads();
  if (t == 0)
    __hip_atomic_store(&blkflag[blockIdx.x], MAGIC,
                       __ATOMIC_RELAXED, __HIP_MEMORY_SCOPE_AGENT);
  if (blockIdx.x != 0) return;

  // ======== block 0: solver ========
  // f-independent init first -> overlaps with the other blocks' scans.
  if (t < Mn) cnt[t] = 0;
  const float xt  = x[t];
  const float th0 = tanhf(0.5f * xt);
  *((float4*)&ods[4 * t]) = make_float4(th0, th0, th0, th0);

  // wait for all 256 block flags (bypass loads; no cache invalidates)
  if (t < 256) {
    while (__hip_atomic_load(&blkflag[t], __ATOMIC_RELAXED,
                             __HIP_MEMORY_SCOPE_AGENT) != MAGIC)
      __builtin_amdgcn_s_sleep(2);
  }
  __syncthreads();  // all flags seen -> all f_g bypass stores are at MALL

  // ---- load f (bypass loads; f never transits L1/L2) ----
  int4 fv;
  fv.x = __hip_atomic_load(&f_g[4 * t + 0], __ATOMIC_RELAXED, __HIP_MEMORY_SCOPE_AGENT);
  fv.y = __hip_atomic_load(&f_g[4 * t + 1], __ATOMIC_RELAXED, __HIP_MEMORY_SCOPE_AGENT);
  fv.z = __hip_atomic_load(&f_g[4 * t + 2], __ATOMIC_RELAXED, __HIP_MEMORY_SCOPE_AGENT);
  fv.w = __hip_atomic_load(&f_g[4 * t + 3], __ATOMIC_RELAXED, __HIP_MEMORY_SCOPE_AGENT);
  *((int4*)&fs[4 * t]) = fv;
  __syncthreads();

  // ---- derive keys, assign check slots (ballot scan) ----
  const int fearr[4] = {fv.x, fv.y, fv.z, fv.w};
  int  keys[4];
  bool ismin[4];
#pragma unroll
  for (int k = 0; k < 4; ++k) {
    int e   = 4 * t + k;
    int fe  = fearr[k];
    int ffe = fs[fe];
    keys[k]  = (ffe == e && e < fe) ? e : fe;  // check's minimum edge
    ismin[k] = (keys[k] == e);
  }
  // unique slot per min-edge: wave-local rank via ballot+popcount, then
  // per-wave base via a tiny LDS scan. Slot ordering is arbitrary.
  const unsigned long long ltmask = (1ull << lane) - 1ull;
  int pre = 0;
  int rank[4];
#pragma unroll
  for (int k = 0; k < 4; ++k) {
    unsigned long long b = __ballot(ismin[k]);
    rank[k] = pre + (int)__popcll(b & ltmask);
    pre    += (int)__popcll(b);
  }
  if (lane == 0) wtot[wv] = pre;
  __syncthreads();
  int wbase = 0;
  for (int w2 = 0; w2 < wv; ++w2) wbase += wtot[w2];  // broadcast LDS reads
#pragma unroll
  for (int k = 0; k < 4; ++k)
    if (ismin[k]) slotmap[4 * t + k] = wbase + rank[k];
  __syncthreads();

  // ---- scatter edges into their check's list (unordered) ----
#pragma unroll
  for (int k = 0; k < 4; ++k) {
    int c = slotmap[keys[k]];
    int p = atomicAdd(&cnt[c], 1);
    ce[c * 8 + p] = 4 * t + k;
  }
  __syncthreads();

  // ---- restore ascending edge order: Batcher 8-sorter, registers only ----
  if (t < Mn) {
    int4 a = *((int4*)&ce[t * 8]);
    int4 b = *((int4*)&ce[t * 8 + 4]);
    int s0 = a.x, s1 = a.y, s2 = a.z, s3 = a.w;
    int s4 = b.x, s5 = b.y, s6 = b.z, s7 = b.w;
#define CEX(p, q) { int lo_ = min(p, q), hi_ = max(p, q); p = lo_; q = hi_; }
    CEX(s0, s1); CEX(s2, s3); CEX(s0, s2); CEX(s1, s3); CEX(s1, s2);  // sort lo
    CEX(s4, s5); CEX(s6, s7); CEX(s4, s6); CEX(s5, s7); CEX(s5, s6);  // sort hi
    CEX(s0, s4); CEX(s2, s6); CEX(s1, s5); CEX(s3, s7);               // merge
    CEX(s2, s4); CEX(s3, s5);
    CEX(s1, s2); CEX(s3, s4); CEX(s5, s6);
#undef CEX
    *((int4*)&ce[t * 8])     = make_int4(s0, s1, s2, s3);
    *((int4*)&ce[t * 8 + 4]) = make_int4(s4, s5, s6, s7);
  }
  __syncthreads();

  // ---- BP iterations (bitwise-identical to reference ordering) ----
  const int c = t >> 1;   // check owned by this thread pair
  const int h = t & 1;    // which half of the 8 outputs this thread emits
  int e[8];
#pragma unroll
  for (int k = 0; k < 8; ++k) e[k] = ce[c * 8 + k];  // loop-invariant
  int eo[4];
#pragma unroll
  for (int kk = 0; kk < 4; ++kk) eo[kk] = h ? e[4 + kk] : e[kk];

  for (int it = 0; it < 5; ++it) {
    // even phase: every thread computes all 8 leave-one-out products
    // (exact same multiply sequence as np.prod), then atanhf for only
    // its half -> 4 transcendentals/thread, all 16 waves busy.
    float f[8];
#pragma unroll
    for (int k = 0; k < 8; ++k) {
      float o = ods[e[k]];
      f[k] = (o == 0.0f) ? 1.0f : o;  // reference's zero->identity subst
    }
    float v[8];
    float p = 1.0f;
#pragma unroll
    for (int k = 0; k < 8; ++k) {
      float vv = p;                   // p = ((1*f0)*f1)*...*f[k-1] (exact prefix)
#pragma unroll
      for (int j = k + 1; j < 8; ++j) vv *= f[j];  // continue left-to-right
      v[k] = vv;
      p *= f[k];
    }
#pragma unroll
    for (int kk = 0; kk < 4; ++kk) {
      float vv = h ? v[4 + kk] : v[kk];
      if (vv >= 1.0f)       vv =  1.0f - EPSF;
      else if (vv <= -1.0f) vv = -1.0f + EPSF;
      evs[eo[kk]] = 2.0f * atanhf(vv);
    }
    __syncthreads();

    if (it < 4) {
      float4 e4 = *((const float4*)&evs[4 * t]);
      float ev[4] = {e4.x, e4.y, e4.z, e4.w};
      float od[4];
#pragma unroll
      for (int k = 0; k < 4; ++k) {
        float s = 0.0f;
#pragma unroll
        for (int j = 0; j < 4; ++j)
          if (j != k) s += ev[j];  // ascending 3-term sum, same op order
        od[k] = tanhf(0.5f * (xt + s));
      }
      *((float4*)&ods[4 * t]) = make_float4(od[0], od[1], od[2], od[3]);
      __syncthreads();
    }
  }

  // ---- output: sigmoid(x + sum of final evens), same op order ----
  float4 e4 = *((const float4*)&evs[4 * t]);
  float s4  = e4.x + e4.y + e4.z + e4.w;
  float z   = xt + s4;
  out[t]    = 1.0f / (1.0f + expf(-z));
}

// ---------------------------------------------------------------------------
extern "C" void kernel_launch(void* const* d_in, const int* in_sizes, int n_in,
                              void* d_out, int out_size, void* d_ws,
                              size_t ws_size, hipStream_t stream) {
  const float* x    = (const float*)d_in[0];  // [1024]
  const float* w_oe = (const float*)d_in[2];  // w_odd_to_even [4096,4096]
  float* out = (float*)d_out;

  int* f       = (int*)d_ws;        // [4096] leftmost peer per edge
  int* blkflag = (int*)d_ws + En;   // [256]  per-block completion flags

  spa_fused<<<dim3(256), dim3(1024), 0, stream>>>(w_oe, x, out, f, blkflag);
}

// Round 4
// 168.512 us; speedup vs baseline: 1.6249x; 1.0383x over previous
//
#include <hip/hip_runtime.h>

// SpaNn belief-propagation decoder, sparse reformulation (round 6).
// N=1024 vars x DV=4 edges = E=4096; M=512 checks x DC=8.
// var_of_edge[e] = e>>2 (static). Check connectivity recovered from
// w_odd_to_even via each row's leftmost nonzero column f[e]:
// for a check with edges e1<e2<...<e8, f(e1)=e2 and f(ek>=2)=e1, so
//   key(e) = (f(f(e))==e && e<f(e)) ? e : f(e)
// maps every edge to its check's minimum edge.
//
// Round-6 change: MULTI-CU SOLVE. R3 showed the solver is transcendental-
// bound on ONE CU (~40 us of the 44 us kernel). Now 16 co-resident solver
// blocks each own 32 checks / 64 vars; messages transit workspace via
// RELAXED/AGENT bypass atomics (R2 proved fences catastrophic; R3 proved
// relaxed bypass cheap+correct). Phase barriers: write-once MAGIC tokens,
// one slot per (barrier, block) — __syncthreads' vmcnt(0) drain before the
// token store gives the ordering (R3-validated protocol). Preamble is
// replicated per solver block (deterministic: ballot ranks are functions
// of f only; the Batcher sort canonicalizes the atomic scatter).
// All FP op sequences bitwise-identical to rounds 2-5 (absmax 0.0):
// the per-k product starts at f0/f1 instead of 1.0f*f0 — exact identity.

#define En 4096
#define Nn 1024
#define Mn 512
#define EPSF 1.1920929e-07f
#define MAGIC 0x7E57A11F
#define NSOLVE 16
#define CPB (Mn / NSOLVE)  // 32 checks per solver block
#define VPB (Nn / NSOLVE)  // 64 vars per solver block

__device__ __forceinline__ int ldi_b(const int* p) {
  return __hip_atomic_load(p, __ATOMIC_RELAXED, __HIP_MEMORY_SCOPE_AGENT);
}
__device__ __forceinline__ float ldf_b(const float* p) {
  return __hip_atomic_load(p, __ATOMIC_RELAXED, __HIP_MEMORY_SCOPE_AGENT);
}
__device__ __forceinline__ void sti_b(int* p, int v) {
  __hip_atomic_store(p, v, __ATOMIC_RELAXED, __HIP_MEMORY_SCOPE_AGENT);
}
__device__ __forceinline__ void stf_b(float* p, float v) {
  __hip_atomic_store(p, v, __ATOMIC_RELAXED, __HIP_MEMORY_SCOPE_AGENT);
}

// 16-block token barrier. First __syncthreads lowers with s_waitcnt
// vmcnt(0): all this block's bypass data-stores are at the MALL before the
// token goes up. Tokens are written exactly once per dispatch (fresh
// poison each iteration; poison != MAGIC, proven R3). Deadlock-free: all
// 16 solver blocks are co-resident (1 block/CU) and hit every barrier.
__device__ __forceinline__ void gbar(int* arrive, int bar, int t, int b) {
  __syncthreads();
  if (t == 0) sti_b(&arrive[bar * NSOLVE + b], MAGIC);
  if (t < NSOLVE) {
    while (ldi_b(&arrive[bar * NSOLVE + t]) != MAGIC)
      __builtin_amdgcn_s_sleep(1);
  }
  __syncthreads();
}

__global__ __launch_bounds__(1024) void spa_fused(
    const float* __restrict__ w, const float* __restrict__ x,
    float* __restrict__ out, int* __restrict__ f_g,
    int* __restrict__ sflag, float* __restrict__ ods_g,
    float* __restrict__ evs_g, int* __restrict__ arrive) {
  __shared__ int   fs[En];       // 16 KB  leftmost-peer
  __shared__ int   slotmap[En];  // 16 KB  min-edge -> check slot
  __shared__ int   ce[En];       // 16 KB  check -> 8 edges (ascending)
  __shared__ int   cnt[Mn];      //  2 KB  fill position per check
  __shared__ int   wtot[16];
  __shared__ float xch[256];     //  1 KB  per-phase exchange tile

  const int t    = threadIdx.x;
  const int lane = t & 63;
  const int wv   = t >> 6;
  const int b    = blockIdx.x;

  // ======== phase 1: every block scans 16 rows, one wave per row ========
  // (unchanged from R3 — 1 KB chunks, ballot exit, 4 chunks in flight)
  {
    const int row = b * 16 + wv;
    const float4* rowp = (const float4*)(w + (size_t)row * En);
    float4 v0 = rowp[lane];
    float4 v1 = rowp[64 + lane];
    float4 v2 = rowp[128 + lane];
    float4 v3 = rowp[192 + lane];
    for (int base = 0;; base += 256) {
      bool any = (v0.x != 0.0f) | (v0.y != 0.0f) | (v0.z != 0.0f) | (v0.w != 0.0f);
      unsigned long long m = __ballot(any);
      if (m) {
        if (lane == __ffsll(m) - 1) {
          int off = (v0.x != 0.0f) ? 0 : (v0.y != 0.0f) ? 1 : (v0.z != 0.0f) ? 2 : 3;
          sti_b(&f_g[row], base + 4 * lane + off);  // bypass, no fence
        }
        break;
      }
      v0 = v1; v1 = v2; v2 = v3;
      int nxt = base + 1024;
      if (nxt > En - 256) nxt = En - 256;  // clamp: redundant, never OOB
      v3 = rowp[(nxt >> 2) + lane];
    }
  }
  __syncthreads();  // vmcnt(0): block's 16 f-stores are at the MALL
  if (t == 0) sti_b(&sflag[b], MAGIC);
  if (b >= NSOLVE) return;

  // ======== solver blocks 0..15 ========
  if (t < Mn) cnt[t] = 0;

  // wait for all 256 scan blocks (bypass loads, no invalidates)
  if (t < 256) {
    while (ldi_b(&sflag[t]) != MAGIC) __builtin_amdgcn_s_sleep(2);
  }
  __syncthreads();

  // ---- preamble (replicated per solver block; deterministic) ----
  int4 fv;
  fv.x = ldi_b(&f_g[4 * t + 0]);
  fv.y = ldi_b(&f_g[4 * t + 1]);
  fv.z = ldi_b(&f_g[4 * t + 2]);
  fv.w = ldi_b(&f_g[4 * t + 3]);
  *((int4*)&fs[4 * t]) = fv;
  __syncthreads();

  const int fearr[4] = {fv.x, fv.y, fv.z, fv.w};
  int  keys[4];
  bool ismin[4];
#pragma unroll
  for (int k = 0; k < 4; ++k) {
    int e   = 4 * t + k;
    int fe  = fearr[k];
    int ffe = fs[fe];
    keys[k]  = (ffe == e && e < fe) ? e : fe;  // check's minimum edge
    ismin[k] = (keys[k] == e);
  }
  const unsigned long long ltmask = (1ull << lane) - 1ull;
  int pre = 0;
  int rank[4];
#pragma unroll
  for (int k = 0; k < 4; ++k) {
    unsigned long long bb = __ballot(ismin[k]);
    rank[k] = pre + (int)__popcll(bb & ltmask);
    pre    += (int)__popcll(bb);
  }
  if (lane == 0) wtot[wv] = pre;
  __syncthreads();
  int wbase = 0;
  for (int w2 = 0; w2 < wv; ++w2) wbase += wtot[w2];
#pragma unroll
  for (int k = 0; k < 4; ++k)
    if (ismin[k]) slotmap[4 * t + k] = wbase + rank[k];
  __syncthreads();

#pragma unroll
  for (int k = 0; k < 4; ++k) {
    int c = slotmap[keys[k]];
    int p = atomicAdd(&cnt[c], 1);
    ce[c * 8 + p] = 4 * t + k;
  }
  __syncthreads();

  if (t < Mn) {  // Batcher 8-sorter, registers only (canonicalizes order)
    int4 a = *((int4*)&ce[t * 8]);
    int4 bq = *((int4*)&ce[t * 8 + 4]);
    int s0 = a.x, s1 = a.y, s2 = a.z, s3 = a.w;
    int s4 = bq.x, s5 = bq.y, s6 = bq.z, s7 = bq.w;
#define CEX(p, q) { int lo_ = min(p, q), hi_ = max(p, q); p = lo_; q = hi_; }
    CEX(s0, s1); CEX(s2, s3); CEX(s0, s2); CEX(s1, s3); CEX(s1, s2);
    CEX(s4, s5); CEX(s6, s7); CEX(s4, s6); CEX(s5, s7); CEX(s5, s6);
    CEX(s0, s4); CEX(s2, s6); CEX(s1, s5); CEX(s3, s7);
    CEX(s2, s4); CEX(s3, s5);
    CEX(s1, s2); CEX(s3, s4); CEX(s5, s6);
#undef CEX
    *((int4*)&ce[t * 8])     = make_int4(s0, s1, s2, s3);
    *((int4*)&ce[t * 8 + 4]) = make_int4(s4, s5, s6, s7);
  }
  __syncthreads();

  // ---- per-thread solver roles (loop-invariant) ----
  // even: 8 threads/check -> 256 threads cover CPB=32 checks
  // odd/init: 4 threads/var -> 256 threads cover VPB=64 vars
  int   eedge = 0, ek = 0;
  int   vk = 0;
  float xt_v = 0.0f;
  int   myv = 0;
  if (t < 256) {
    ek    = t & 7;
    eedge = ce[(b * CPB + (t >> 3)) * 8 + ek];
    vk    = t & 3;
    myv   = b * VPB + (t >> 2);
    xt_v  = x[myv];  // input: normal cached load
  }

  // ---- init odd messages for own vars: ods = tanh(0.5*x) ----
  if (t < 256) stf_b(&ods_g[4 * myv + vk], tanhf(0.5f * xt_v));
  gbar(arrive, 0, t, b);

  // ---- 5 BP iterations, bitwise-identical op ordering ----
  for (int it = 0; it < 5; ++it) {
    // even: leave-one-out product over the check's 8 odd messages
    if (t < 256) {
      float o = ldf_b(&ods_g[eedge]);
      xch[t] = (o == 0.0f) ? 1.0f : o;  // reference's zero->identity subst
    }
    __syncthreads();
    if (t < 256) {
      int gb = t & ~7;
      int j0 = (ek == 0) ? 1 : 0;
      float p = xch[gb + j0];            // == 1.0f*f[j0] bitwise
      for (int j = j0 + 1; j < 8; ++j)
        if (j != ek) p *= xch[gb + j];   // ascending, skip self (np.prod order)
      if (p >= 1.0f)       p =  1.0f - EPSF;
      else if (p <= -1.0f) p = -1.0f + EPSF;
      stf_b(&evs_g[eedge], 2.0f * atanhf(p));
    }
    gbar(arrive, 1 + 2 * it, t, b);

    if (it < 4) {
      // odd: var-node update from 3 extrinsic even messages
      if (t < 256) xch[t] = ldf_b(&evs_g[4 * myv + vk]);
      __syncthreads();
      if (t < 256) {
        int qb = t & ~3;
        float s = 0.0f;
        for (int j = 0; j < 4; ++j)
          if (j != vk) s += xch[qb + j];  // ascending 3-term sum
        stf_b(&ods_g[4 * myv + vk], tanhf(0.5f * (xt_v + s)));
      }
      gbar(arrive, 2 + 2 * it, t, b);
    }
  }

  // ---- output: sigmoid(x + sum of final evens), own 64 vars ----
  if (t < 64) {
    int v = b * VPB + t;
    float e0 = ldf_b(&evs_g[4 * v + 0]);
    float e1 = ldf_b(&evs_g[4 * v + 1]);
    float e2 = ldf_b(&evs_g[4 * v + 2]);
    float e3 = ldf_b(&evs_g[4 * v + 3]);
    float s4 = ((e0 + e1) + e2) + e3;
    float z  = x[v] + s4;
    out[v]   = 1.0f / (1.0f + expf(-z));
  }
}

// ---------------------------------------------------------------------------
extern "C" void kernel_launch(void* const* d_in, const int* in_sizes, int n_in,
                              void* d_out, int out_size, void* d_ws,
                              size_t ws_size, hipStream_t stream) {
  const float* x    = (const float*)d_in[0];  // [1024]
  const float* w_oe = (const float*)d_in[2];  // w_odd_to_even [4096,4096]
  float* out = (float*)d_out;

  int*   f      = (int*)d_ws;             // [4096] leftmost peer per edge
  int*   sflag  = f + En;                 // [256]  scan-done flags
  float* ods_g  = (float*)(sflag + 256);  // [4096] odd messages (bypass)
  float* evs_g  = ods_g + En;             // [4096] even messages (bypass)
  int*   arrive = (int*)(evs_g + En);     // [10*16] barrier tokens

  spa_fused<<<dim3(256), dim3(1024), 0, stream>>>(w_oe, x, out, f, sflag,
                                                  ods_g, evs_g, arrive);
}

// Round 5
// 163.981 us; speedup vs baseline: 1.6698x; 1.0276x over previous
//
#include <hip/hip_runtime.h>

// SpaNn belief-propagation decoder, sparse reformulation (round 7).
// N=1024 vars x DV=4 edges = E=4096; M=512 checks x DC=8.
// var_of_edge[e] = e>>2 (static). Check connectivity recovered from
// w_odd_to_even via each row's leftmost nonzero column f[e]:
// for a check with edges e1<e2<...<e8, f(e1)=e2 and f(ek>=2)=e1, so
//   key(e) = (f(f(e))==e && e<f(e)) ? e : f(e)
// maps every edge to its check's minimum edge.
//
// Round-7 change: CONSUMER-SIDE ODD PHASE. R4 showed each global phase
// boundary costs ~2.5-3 us (token barrier + bypass round trips), 10 of
// them ~= 27 us. Each edge's odd message has exactly ONE consumer (its
// check's even phase), so the odd update moves into the consumer block:
// od(e) = tanhf(0.5*(x[v] + sum_{j!=k} evs[4v+j])). ods never touches
// memory; only evs transits globally; barriers drop 10 -> 5.
// Sync protocol unchanged from R3/R4 (validated): RELAXED/AGENT bypass
// atomics, __syncthreads' vmcnt(0) drain orders data before write-once
// MAGIC tokens; fresh poison != MAGIC each harness iteration.
// All FP op sequences bitwise-identical to rounds 2-6 (absmax 0.0).

#define En 4096
#define Nn 1024
#define Mn 512
#define EPSF 1.1920929e-07f
#define MAGIC 0x7E57A11F
#define NSOLVE 16
#define CPB (Mn / NSOLVE)  // 32 checks per solver block
#define VPB (Nn / NSOLVE)  // 64 output vars per solver block

__device__ __forceinline__ int ldi_b(const int* p) {
  return __hip_atomic_load(p, __ATOMIC_RELAXED, __HIP_MEMORY_SCOPE_AGENT);
}
__device__ __forceinline__ float ldf_b(const float* p) {
  return __hip_atomic_load(p, __ATOMIC_RELAXED, __HIP_MEMORY_SCOPE_AGENT);
}
__device__ __forceinline__ void sti_b(int* p, int v) {
  __hip_atomic_store(p, v, __ATOMIC_RELAXED, __HIP_MEMORY_SCOPE_AGENT);
}
__device__ __forceinline__ void stf_b(float* p, float v) {
  __hip_atomic_store(p, v, __ATOMIC_RELAXED, __HIP_MEMORY_SCOPE_AGENT);
}

// 16-block token barrier (R3/R4-validated). First __syncthreads lowers
// with s_waitcnt vmcnt(0): all of this block's bypass data-stores are at
// the MALL before the token goes up. Write-once per (barrier, block).
__device__ __forceinline__ void gbar(int* arrive, int bar, int t, int b) {
  __syncthreads();
  if (t == 0) sti_b(&arrive[bar * NSOLVE + b], MAGIC);
  if (t < NSOLVE) {
    while (ldi_b(&arrive[bar * NSOLVE + t]) != MAGIC)
      __builtin_amdgcn_s_sleep(1);
  }
  __syncthreads();
}

__global__ __launch_bounds__(1024) void spa_fused(
    const float* __restrict__ w, const float* __restrict__ x,
    float* __restrict__ out, int* __restrict__ f_g,
    int* __restrict__ sflag, float* __restrict__ evs_g,
    int* __restrict__ arrive) {
  __shared__ int   fs[En];       // 16 KB  leftmost-peer
  __shared__ int   slotmap[En];  // 16 KB  min-edge -> check slot
  __shared__ int   ce[En];       // 16 KB  check -> 8 edges (ascending)
  __shared__ int   cnt[Mn];      //  2 KB  fill position per check
  __shared__ int   wtot[16];
  __shared__ float xch[256];     //  1 KB  even-phase product inputs

  const int t    = threadIdx.x;
  const int lane = t & 63;
  const int wv   = t >> 6;
  const int b    = blockIdx.x;

  // ======== phase 1: every block scans 16 rows, one wave per row ========
  // (unchanged from R3/R4 — 1 KB chunks, ballot exit, 4 chunks in flight)
  {
    const int row = b * 16 + wv;
    const float4* rowp = (const float4*)(w + (size_t)row * En);
    float4 v0 = rowp[lane];
    float4 v1 = rowp[64 + lane];
    float4 v2 = rowp[128 + lane];
    float4 v3 = rowp[192 + lane];
    for (int base = 0;; base += 256) {
      bool any = (v0.x != 0.0f) | (v0.y != 0.0f) | (v0.z != 0.0f) | (v0.w != 0.0f);
      unsigned long long m = __ballot(any);
      if (m) {
        if (lane == __ffsll(m) - 1) {
          int off = (v0.x != 0.0f) ? 0 : (v0.y != 0.0f) ? 1 : (v0.z != 0.0f) ? 2 : 3;
          sti_b(&f_g[row], base + 4 * lane + off);  // bypass, no fence
        }
        break;
      }
      v0 = v1; v1 = v2; v2 = v3;
      int nxt = base + 1024;
      if (nxt > En - 256) nxt = En - 256;  // clamp: redundant, never OOB
      v3 = rowp[(nxt >> 2) + lane];
    }
  }
  __syncthreads();  // vmcnt(0): block's 16 f-stores are at the MALL
  if (t == 0) sti_b(&sflag[b], MAGIC);
  if (b >= NSOLVE) return;

  // ======== solver blocks 0..15 ========
  if (t < Mn) cnt[t] = 0;

  // wait for all 256 scan blocks (bypass loads, no invalidates)
  if (t < 256) {
    while (ldi_b(&sflag[t]) != MAGIC) __builtin_amdgcn_s_sleep(2);
  }
  __syncthreads();

  // ---- preamble (replicated per solver block; deterministic) ----
  int4 fv;
  fv.x = ldi_b(&f_g[4 * t + 0]);
  fv.y = ldi_b(&f_g[4 * t + 1]);
  fv.z = ldi_b(&f_g[4 * t + 2]);
  fv.w = ldi_b(&f_g[4 * t + 3]);
  *((int4*)&fs[4 * t]) = fv;
  __syncthreads();

  const int fearr[4] = {fv.x, fv.y, fv.z, fv.w};
  int  keys[4];
  bool ismin[4];
#pragma unroll
  for (int k = 0; k < 4; ++k) {
    int e   = 4 * t + k;
    int fe  = fearr[k];
    int ffe = fs[fe];
    keys[k]  = (ffe == e && e < fe) ? e : fe;  // check's minimum edge
    ismin[k] = (keys[k] == e);
  }
  const unsigned long long ltmask = (1ull << lane) - 1ull;
  int pre = 0;
  int rank[4];
#pragma unroll
  for (int k = 0; k < 4; ++k) {
    unsigned long long bb = __ballot(ismin[k]);
    rank[k] = pre + (int)__popcll(bb & ltmask);
    pre    += (int)__popcll(bb);
  }
  if (lane == 0) wtot[wv] = pre;
  __syncthreads();
  int wbase = 0;
  for (int w2 = 0; w2 < wv; ++w2) wbase += wtot[w2];
#pragma unroll
  for (int k = 0; k < 4; ++k)
    if (ismin[k]) slotmap[4 * t + k] = wbase + rank[k];
  __syncthreads();

#pragma unroll
  for (int k = 0; k < 4; ++k) {
    int c = slotmap[keys[k]];
    int p = atomicAdd(&cnt[c], 1);
    ce[c * 8 + p] = 4 * t + k;
  }
  __syncthreads();

  if (t < Mn) {  // Batcher 8-sorter, registers only (canonicalizes order)
    int4 a = *((int4*)&ce[t * 8]);
    int4 bq = *((int4*)&ce[t * 8 + 4]);
    int s0 = a.x, s1 = a.y, s2 = a.z, s3 = a.w;
    int s4 = bq.x, s5 = bq.y, s6 = bq.z, s7 = bq.w;
#define CEX(p, q) { int lo_ = min(p, q), hi_ = max(p, q); p = lo_; q = hi_; }
    CEX(s0, s1); CEX(s2, s3); CEX(s0, s2); CEX(s1, s3); CEX(s1, s2);
    CEX(s4, s5); CEX(s6, s7); CEX(s4, s6); CEX(s5, s7); CEX(s5, s6);
    CEX(s0, s4); CEX(s2, s6); CEX(s1, s5); CEX(s3, s7);
    CEX(s2, s4); CEX(s3, s5);
    CEX(s1, s2); CEX(s3, s4); CEX(s5, s6);
#undef CEX
    *((int4*)&ce[t * 8])     = make_int4(s0, s1, s2, s3);
    *((int4*)&ce[t * 8 + 4]) = make_int4(s4, s5, s6, s7);
  }
  __syncthreads();

  // ---- per-thread role: thread t < 256 owns edge ce[b*256 + t] ----
  // (my checks are b*CPB .. b*CPB+31; their 256 edges are contiguous in ce,
  //  sorted ascending within each check -> group of 8 threads = one check)
  int   e = 0, kv = 0, vhome = 0;
  float xv = 0.0f, od = 0.0f;
  if (t < 256) {
    e     = ce[b * 256 + t];
    vhome = e >> 2;
    kv    = e & 3;
    xv    = x[vhome];               // cached load (read-only input)
    od    = tanhf(0.5f * xv);       // iter-1 odd message (== reference init)
  }

  // ---- 5 BP iterations: even publishes evs, odd is consumer-side ----
  for (int it = 0; it < 5; ++it) {
    // even: leave-one-out product over the check's 8 odd messages
    if (t < 256) xch[t] = (od == 0.0f) ? 1.0f : od;  // zero->identity subst
    __syncthreads();
    if (t < 256) {
      int gb = t & ~7;
      int ek = t & 7;
      int j0 = (ek == 0) ? 1 : 0;
      float p = xch[gb + j0];            // == 1.0f*f[j0] bitwise
      for (int j = j0 + 1; j < 8; ++j)
        if (j != ek) p *= xch[gb + j];   // ascending, skip self (np.prod)
      if (p >= 1.0f)       p =  1.0f - EPSF;
      else if (p <= -1.0f) p = -1.0f + EPSF;
      stf_b(&evs_g[e], 2.0f * atanhf(p));
    }
    gbar(arrive, it, t, b);  // evs(it) globally visible past here

    if (it < 4) {
      // odd, consumer-side: extrinsic sum of my edge's 3 siblings
      if (t < 256) {
        float s = 0.0f;
        for (int j = 0; j < 4; ++j)
          if (j != kv) s += ldf_b(&evs_g[4 * vhome + j]);  // ascending
        od = tanhf(0.5f * (xv + s));
      }
    }
  }

  // ---- output: sigmoid(x + sum of final evens), own 64 vars ----
  if (t < VPB) {
    int v = b * VPB + t;
    float e0 = ldf_b(&evs_g[4 * v + 0]);
    float e1 = ldf_b(&evs_g[4 * v + 1]);
    float e2 = ldf_b(&evs_g[4 * v + 2]);
    float e3 = ldf_b(&evs_g[4 * v + 3]);
    float s4 = ((e0 + e1) + e2) + e3;
    float z  = x[v] + s4;
    out[v]   = 1.0f / (1.0f + expf(-z));
  }
}

// ---------------------------------------------------------------------------
extern "C" void kernel_launch(void* const* d_in, const int* in_sizes, int n_in,
                              void* d_out, int out_size, void* d_ws,
                              size_t ws_size, hipStream_t stream) {
  const float* x    = (const float*)d_in[0];  // [1024]
  const float* w_oe = (const float*)d_in[2];  // w_odd_to_even [4096,4096]
  float* out = (float*)d_out;

  int*   f      = (int*)d_ws;             // [4096] leftmost peer per edge
  int*   sflag  = f + En;                 // [256]  scan-done flags
  float* evs_g  = (float*)(sflag + 256);  // [4096] even messages (bypass)
  int*   arrive = (int*)(evs_g + En);     // [5*16] barrier tokens

  spa_fused<<<dim3(256), dim3(1024), 0, stream>>>(w_oe, x, out, f, sflag,
                                                  evs_g, arrive);
}